// Round 12
// baseline (241.212 us; speedup 1.0000x reference)
//
#include <hip/hip_runtime.h>
#include <hip/hip_bf16.h>

// Problem constants
#define NB 128       // batch (num_sims)
#define NA 64        // num_atoms
#define NE 4032      // edges = NA*(NA-1)
#define KT 2         // edge types
#define BE (NB * NE) // 516096 rows per edge type
#define DV_SIZE 262144
#define DE_SIZE 16515072
#define ZERO_SIZE 1032192

// Edge pass: 504 blocks * 8 waves * 8 tiles * 16 rows = 516096.
// Round-8: doubling blocks at constant work = +26us (staging+flush overhead).
// Round-12 move: HALVE blocks via 512-thread / 8-wave blocks — staging per
// block serves 8 waves, total staging work /2, dispatch count /2.
#define PBLK_A 504
#define TPW_A 8
#define NODE_BLOCKS 64    // 64 x 8 waves = 512 node tiles

#define EPI_EDGE_BLOCKS 8064   // BE*4 / 256
#define EPI_NODE_BLOCKS 1024   // DV_SIZE / 256
#define EPI_ZERO_BLOCKS 1008   // ZERO_SIZE / (256*4)

typedef __attribute__((ext_vector_type(8))) short short8;
typedef __attribute__((ext_vector_type(4))) float floatx4;

__device__ __forceinline__ float elu(float x) {
    return x > 0.0f ? x : __expf(x) - 1.0f;
}

__device__ __forceinline__ unsigned short f2bf(float x) {  // RNE, one-time staging
    unsigned u = __float_as_uint(x);
    return (unsigned short)((u + 0x7FFFu + ((u >> 16) & 1u)) >> 16);
}

// packed f32x2 -> bf16x2 (RNE): low 16 = a, high 16 = b
__device__ __forceinline__ unsigned pkbf(float a, float b) {
    __hip_bfloat162 h = __float22bfloat162_rn(make_float2(a, b));
    unsigned u;
    __builtin_memcpy(&u, &h, 4);
    return u;
}

__device__ __forceinline__ short8 pack8(float4 a, float4 b) {
    unsigned u[4] = {pkbf(a.x, a.y), pkbf(a.z, a.w), pkbf(b.x, b.y), pkbf(b.z, b.w)};
    short8 r;
    __builtin_memcpy(&r, u, 16);
    return r;
}

// ===========================================================================
// PREP (round-10 proven): agg (blocks 0..255, unroll 8) + v0->bf16 (256..511)
//       + bucket zeroing (block 512). unroll-16 (R11) and 8192-block agg (R9)
//       both measured SLOWER — do not re-attempt.
// ===========================================================================
__global__ __launch_bounds__(256) void prep_kernel(const float* __restrict__ e0,
                                                   float* __restrict__ agg,
                                                   const float* __restrict__ v0,
                                                   unsigned short* __restrict__ v0bf,
                                                   float* __restrict__ buckets) {
    if (blockIdx.x < 256) {
        // agg[b,j,c4] = (1/64) * sum_{i != j} e0[b, i, pos(i,j), c4]
        const int f = blockIdx.x * 256 + threadIdx.x;  // 65536 = B*N*8
        const int c4 = f & 7;
        const int jn = (f >> 3) & 63;
        const int b = f >> 9;
        const float4* base = (const float4*)e0 + (size_t)b * 64 * 63 * 8;
        float x = 0.f, y = 0.f, z = 0.f, ww = 0.f;
#pragma unroll 8
        for (int i = 0; i < 64; i++) {
            int p = jn - (jn > i ? 1 : 0);
            p = p > 62 ? 62 : p;
            const float m = (i == jn) ? 0.0f : 1.0f;
            const float4 v = base[(i * 63 + p) * 8 + c4];
            x = fmaf(v.x, m, x);
            y = fmaf(v.y, m, y);
            z = fmaf(v.z, m, z);
            ww = fmaf(v.w, m, ww);
        }
        const float s = 1.0f / 64.0f;
        *(float4*)(agg + (size_t)f * 4) = make_float4(x * s, y * s, z * s, ww * s);
    } else if (blockIdx.x < 512) {
        const int idx = (blockIdx.x - 256) * 256 + threadIdx.x;  // 65536, 4 elems each
        const float4 v = reinterpret_cast<const float4*>(v0)[idx];
        uint2 r;
        r.x = pkbf(v.x, v.y);
        r.y = pkbf(v.z, v.w);
        reinterpret_cast<uint2*>(v0bf)[idx] = r;
    } else {
        // zero edge+node BN buckets: 6144 floats = 1536 float4
#pragma unroll
        for (int it = 0; it < 6; it++) {
            const int i4 = it * 256 + threadIdx.x;
            *(float4*)(buckets + (size_t)i4 * 4) = make_float4(0.f, 0.f, 0.f, 0.f);
        }
    }
}

// ===========================================================================
// MERGED MFMA pass, 512-thread / 8-wave blocks:
//   blocks [0,504)   = edge MLP (same per-wave work as round-10's 65us kernel;
//                      staging serves 8 waves -> total staging work /2)
//   blocks [504,568) = node MLP
// LDS = 41,728 B (8-wave hbuf) -> 3 blocks/CU allowed; ~2/CU grid-limited =
// 16 waves/CU, same as round-10 -> isolates the block-overhead effect.
// History: 2016x256t grids SLOWER (rounds 3/8); (256,6) spill disaster (r1);
// bias->VGPR + manual prefetch slower (r7); epilogue chunking slower (r11).
// ===========================================================================
struct SMW {
    short8 wA1[16][64];  // f = ((k*4+mt)*2+kf)   16 KB
    short8 wA2[8][64];   // f = ((k*2+mt2)*2+kf)   8 KB
    float b1s[128];
    float b2s[64];
};
struct SME {
    SMW wk;
    unsigned hbuf[8][512];  // 16 KB, per-wave fc1->fc2 transpose buffer
};
struct SMN {
    short8 wA1n[4][64];
    short8 wA2n[4][64];
    float b1s[64];
    float b2s[32];
    unsigned long long hbuf[8][16 * 20];
};
union SMU {
    SME e;
    SMN n;
};

__device__ __forceinline__ void stage_weights512(SMW& sm, const float* __restrict__ W1,
                                                 const float* __restrict__ b1,
                                                 const float* __restrict__ W2,
                                                 const float* __restrict__ b2) {
    const int tid = threadIdx.x;  // 0..511
#pragma unroll
    for (int s = 0; s < 2; s++) {
        const int slot = s * 512 + tid;  // 1024 slots
        const int f = slot >> 6, l = slot & 63;
        const int k = f >> 3, mt = (f >> 1) & 3, kf = f & 1;
        const int g = l >> 4, m15 = l & 15;
        short8 v;
#pragma unroll
        for (int j = 0; j < 8; j++) {
            const int kk = kf * 32 + g * 8 + j;
            v[j] = (short)f2bf(W1[(k * 64 + kk) * 64 + mt * 16 + m15]);
        }
        sm.wA1[f][l] = v;
    }
    {
        const int slot = tid;  // 512 slots
        const int f = slot >> 6, l = slot & 63;
        const int k = f >> 2, mt2 = (f >> 1) & 1, kf = f & 1;
        const int g = l >> 4, m15 = l & 15;
        short8 v;
#pragma unroll
        for (int j = 0; j < 8; j++) {
            const int kk = kf * 32 + g * 8 + j;
            v[j] = (short)f2bf(W2[(k * 64 + kk) * 32 + mt2 * 16 + m15]);
        }
        sm.wA2[f][l] = v;
    }
    if (tid < 128) sm.b1s[tid] = b1[tid];
    if (tid < 64) sm.b2s[tid] = b2[tid];
}

__device__ __forceinline__ void load_xfrags(const unsigned short* __restrict__ v0bf,
                                            int row, int g, short8& bx0, short8& bx1) {
    const int b = row / NE;
    const int e = row - b * NE;
    const int i = e / 63;
    const int p = e - i * 63;
    const int j = p + (p >= i ? 1 : 0);
    bx0 = *(const short8*)(v0bf + ((b * 64 + j) * 32 + g * 8));  // recv
    bx1 = *(const short8*)(v0bf + ((b * 64 + i) * 32 + g * 8));  // send
}

__global__ __launch_bounds__(512, 3) void edge_stats_mfma_kernel(
    const unsigned short* __restrict__ v0bf, const float* __restrict__ W1,
    const float* __restrict__ b1, const float* __restrict__ W2,
    const float* __restrict__ b2, float* __restrict__ buckets,
    unsigned short* __restrict__ o_e, const float* __restrict__ agg,
    const float* __restrict__ W1v, const float* __restrict__ b1v,
    const float* __restrict__ W2v, const float* __restrict__ b2v,
    float* __restrict__ o_v, float* __restrict__ nbuckets) {
    __shared__ SMU u;
    const int lane = threadIdx.x & 63;
    const int w = threadIdx.x >> 6;      // 0..7
    const int g = lane >> 4, m15 = lane & 15;

    if (blockIdx.x < PBLK_A) {
        // ================= EDGE PATH =================
        SME& sm = u.e;
        stage_weights512(sm.wk, W1, b1, W2, b2);
        __syncthreads();

        const int gw = blockIdx.x * 8 + w;   // 4032 wave-groups
        unsigned* hw = &sm.hbuf[w][0];
        const int sw = m15 & 7;            // hbuf XOR-swizzle key
        const int rbase = m15 * 32;

#pragma unroll 1
        for (int k = 0; k < 2; k++) {
            // weight frags -> registers (invariant across tiles): 12 short8 = 48 VGPR
            short8 a1r[4][2], a2r[2][2];
#pragma unroll
            for (int mt = 0; mt < 4; mt++)
#pragma unroll
                for (int kf = 0; kf < 2; kf++)
                    a1r[mt][kf] = sm.wk.wA1[(k * 4 + mt) * 2 + kf][lane];
#pragma unroll
            for (int mt2 = 0; mt2 < 2; mt2++)
#pragma unroll
                for (int kf = 0; kf < 2; kf++)
                    a2r[mt2][kf] = sm.wk.wA2[(k * 2 + mt2) * 2 + kf][lane];

            float st[2][4], sq[2][4];
#pragma unroll
            for (int m = 0; m < 2; m++)
#pragma unroll
                for (int r = 0; r < 4; r++) { st[m][r] = 0.f; sq[m][r] = 0.f; }

#pragma unroll 2
            for (int tt = 0; tt < TPW_A; tt++) {
                const int row = (gw * TPW_A + tt) * 16 + m15;
                short8 bx0, bx1;
                load_xfrags(v0bf, row, g, bx0, bx1);

#pragma unroll
                for (int mt = 0; mt < 4; mt++) {
                    const float4 bb = *(const float4*)&sm.wk.b1s[k * 64 + mt * 16 + 4 * g];
                    floatx4 acc = {bb.x, bb.y, bb.z, bb.w};
                    acc = __builtin_amdgcn_mfma_f32_16x16x32_bf16(a1r[mt][0], bx0, acc, 0, 0, 0);
                    acc = __builtin_amdgcn_mfma_f32_16x16x32_bf16(a1r[mt][1], bx1, acc, 0, 0, 0);
                    uint2 hv;
                    hv.x = pkbf(elu(acc[0]), elu(acc[1]));
                    hv.y = pkbf(elu(acc[2]), elu(acc[3]));
                    const int q = 2 * mt + (g >> 1);
                    *(uint2*)&hw[rbase + ((q ^ sw) << 2) + 2 * (g & 1)] = hv;
                }
                const short8 bh0 = *(const short8*)&hw[rbase + (((g) ^ sw) << 2)];
                const short8 bh1 = *(const short8*)&hw[rbase + (((g + 4) ^ sw) << 2)];
#pragma unroll
                for (int mt2 = 0; mt2 < 2; mt2++) {
                    const float4 bb = *(const float4*)&sm.wk.b2s[k * 32 + mt2 * 16 + 4 * g];
                    floatx4 acc = {bb.x, bb.y, bb.z, bb.w};
                    acc = __builtin_amdgcn_mfma_f32_16x16x32_bf16(a2r[mt2][0], bh0, acc, 0, 0, 0);
                    acc = __builtin_amdgcn_mfma_f32_16x16x32_bf16(a2r[mt2][1], bh1, acc, 0, 0, 0);
                    float v0v = elu(acc[0]), v1v = elu(acc[1]);
                    float v2v = elu(acc[2]), v3v = elu(acc[3]);
                    st[mt2][0] += v0v; sq[mt2][0] += v0v * v0v;
                    st[mt2][1] += v1v; sq[mt2][1] += v1v * v1v;
                    st[mt2][2] += v2v; sq[mt2][2] += v2v * v2v;
                    st[mt2][3] += v3v; sq[mt2][3] += v3v * v3v;
                    uint2 ov;
                    ov.x = pkbf(v0v, v1v);
                    ov.y = pkbf(v2v, v3v);
                    *(uint2*)(o_e + ((size_t)k * BE + row) * 32 + mt2 * 16 + 4 * g) = ov;
                }
            }

            // flush stats for this k
            const int bk = gw & 31;
#pragma unroll
            for (int m = 0; m < 2; m++)
#pragma unroll
                for (int r = 0; r < 4; r++) {
                    float s = st[m][r], ss = sq[m][r];
#pragma unroll
                    for (int off = 1; off < 16; off <<= 1) {
                        s += __shfl_xor(s, off, 64);
                        ss += __shfl_xor(ss, off, 64);
                    }
                    if (m15 == 0) {
                        const int ch = m * 16 + 4 * g + r;
                        atomicAdd(&buckets[((bk * KT + k) * 32 + ch) * 2], s);
                        atomicAdd(&buckets[((bk * KT + k) * 32 + ch) * 2 + 1], ss);
                    }
                }
        }
    } else {
        // ================= NODE PATH =================
        SMN& sm = u.n;
        const int tid = threadIdx.x;  // 0..511
        {
            const int f8 = tid >> 6, l = tid & 63;
            const int gg = l >> 4, mm = l & 15;
            if (f8 < 4) {
                short8 v;
#pragma unroll
                for (int j = 0; j < 8; j++)
                    v[j] = (short)f2bf(W1v[(gg * 8 + j) * 64 + f8 * 16 + mm]);
                sm.wA1n[f8][l] = v;
            } else {
                const int f = f8 - 4;
                const int mt2 = f >> 1, kf = f & 1;
                short8 uu;
#pragma unroll
                for (int j = 0; j < 8; j++)
                    uu[j] = (short)f2bf(W2v[(kf * 32 + gg * 8 + j) * 32 + mt2 * 16 + mm]);
                sm.wA2n[f][l] = uu;
            }
        }
        if (tid < 64) sm.b1s[tid] = b1v[tid];
        else if (tid < 96) sm.b2s[tid - 64] = b2v[tid - 64];
        __syncthreads();

        const int tile = (blockIdx.x - PBLK_A) * 8 + w;  // 512 tiles
        const int row = tile * 16 + m15;

        const float4* px = (const float4*)(agg + (size_t)row * 32 + g * 8);
        const short8 bx = pack8(px[0], px[1]);

        const char* hbase = (const char*)&sm.hbuf[w][0];
        unsigned long long* hw = &sm.hbuf[w][0];

#pragma unroll
        for (int mt = 0; mt < 4; mt++) {
            const float4 bb = *(const float4*)&sm.b1s[mt * 16 + 4 * g];
            floatx4 acc = {bb.x, bb.y, bb.z, bb.w};
            acc = __builtin_amdgcn_mfma_f32_16x16x32_bf16(sm.wA1n[mt][lane], bx, acc, 0, 0, 0);
            const unsigned lo = pkbf(elu(acc[0]), elu(acc[1]));
            const unsigned hi = pkbf(elu(acc[2]), elu(acc[3]));
            hw[m15 * 20 + mt * 4 + g] = ((unsigned long long)hi << 32) | lo;
        }
        const short8 bh0 = *(const short8*)(hbase + m15 * 160 + 0 + g * 16);
        const short8 bh1 = *(const short8*)(hbase + m15 * 160 + 64 + g * 16);

        const int bk = tile & 31;
#pragma unroll
        for (int mt2 = 0; mt2 < 2; mt2++) {
            const float4 bb = *(const float4*)&sm.b2s[mt2 * 16 + 4 * g];
            floatx4 acc = {bb.x, bb.y, bb.z, bb.w};
            acc = __builtin_amdgcn_mfma_f32_16x16x32_bf16(sm.wA2n[mt2 * 2 + 0][lane], bh0, acc, 0, 0, 0);
            acc = __builtin_amdgcn_mfma_f32_16x16x32_bf16(sm.wA2n[mt2 * 2 + 1][lane], bh1, acc, 0, 0, 0);
            float4 ov;
            ov.x = elu(acc[0]);
            ov.y = elu(acc[1]);
            ov.z = elu(acc[2]);
            ov.w = elu(acc[3]);
            *(float4*)(o_v + (size_t)row * 32 + mt2 * 16 + 4 * g) = ov;
            const float vv[4] = {ov.x, ov.y, ov.z, ov.w};
#pragma unroll
            for (int r = 0; r < 4; r++) {
                float s = vv[r], ss = vv[r] * vv[r];
#pragma unroll
                for (int off = 1; off < 16; off <<= 1) {
                    s += __shfl_xor(s, off, 64);
                    ss += __shfl_xor(ss, off, 64);
                }
                if (m15 == 0) {
                    const int ch = mt2 * 16 + 4 * g + r;
                    atomicAdd(&nbuckets[(bk * 32 + ch) * 2], s);
                    atomicAdd(&nbuckets[(bk * 32 + ch) * 2 + 1], ss);
                }
            }
        }
    }
}

// ===========================================================================
// EPILOGUE (round-10 proven v1): blocks [0,8064) edge BN-affine+etype -> de;
// blocks [8064,9088) node BN-affine -> dv; blocks [9088,10096) zero third
// output. 4-chunk grid-stride (R11) measured SLOWER — do not re-attempt.
// ===========================================================================
__global__ __launch_bounds__(256) void epilogue_kernel(
    const unsigned short* __restrict__ o_e, const float* __restrict__ etype,
    const float* __restrict__ buckets, const float* __restrict__ ge,
    const float* __restrict__ bte, const float* __restrict__ o_v,
    const float* __restrict__ nbuckets, const float* __restrict__ gv,
    const float* __restrict__ btv, float* __restrict__ out) {
    __shared__ float afs[64], cfs[64];

    if (blockIdx.x < EPI_EDGE_BLOCKS) {
        if (threadIdx.x < 64) {
            const int k = threadIdx.x >> 5, c = threadIdx.x & 31;
            float s = 0.0f, ss = 0.0f;
#pragma unroll
            for (int bk = 0; bk < 32; bk++) {
                s += buckets[((bk * KT + k) * 32 + c) * 2];
                ss += buckets[((bk * KT + k) * 32 + c) * 2 + 1];
            }
            const float M = (float)BE;
            const float mu = s / M;
            const float var = ss / M - mu * mu;
            const float rs = rsqrtf(var + 1e-5f);
            const float af = ge[k * 32 + c] * rs;
            afs[threadIdx.x] = af;
            cfs[threadIdx.x] = bte[k * 32 + c] - mu * af;
        }
        __syncthreads();

        float* de = out + DV_SIZE;
        const int t = blockIdx.x * 256 + threadIdx.x;  // BE*4 = 2064384
        const int cg = t & 3;
        const int row = t >> 2;
        const uint4 p0 = *(const uint4*)(o_e + (size_t)row * 32 + cg * 8);
        const uint4 p1 = *(const uint4*)(o_e + ((size_t)BE + row) * 32 + cg * 8);
        const float2 wv = *(const float2*)(etype + (size_t)row * 2);
        const unsigned pu0[4] = {p0.x, p0.y, p0.z, p0.w};
        const unsigned pu1[4] = {p1.x, p1.y, p1.z, p1.w};

        float r[8];
#pragma unroll
        for (int uu = 0; uu < 8; uu++) {
            const int ch = cg * 8 + uu;
            const float o0 = __uint_as_float((uu & 1) ? (pu0[uu >> 1] & 0xFFFF0000u)
                                                      : (pu0[uu >> 1] << 16));
            const float o1 = __uint_as_float((uu & 1) ? (pu1[uu >> 1] & 0xFFFF0000u)
                                                      : (pu1[uu >> 1] << 16));
            r[uu] = wv.x * fmaf(afs[ch], o0, cfs[ch]) +
                    wv.y * fmaf(afs[32 + ch], o1, cfs[32 + ch]);
        }
        float4* dst = (float4*)(de + (size_t)row * 32 + cg * 8);
        dst[0] = make_float4(r[0], r[1], r[2], r[3]);
        dst[1] = make_float4(r[4], r[5], r[6], r[7]);
    } else if (blockIdx.x < EPI_EDGE_BLOCKS + EPI_NODE_BLOCKS) {
        if (threadIdx.x < 32) {
            const int c = threadIdx.x;
            float s = 0.0f, ss = 0.0f;
#pragma unroll
            for (int bk = 0; bk < 32; bk++) {
                s += nbuckets[(bk * 32 + c) * 2];
                ss += nbuckets[(bk * 32 + c) * 2 + 1];
            }
            const float M = 8192.0f;
            const float mu = s / M;
            const float var = ss / M - mu * mu;
            const float rs = rsqrtf(var + 1e-5f);
            const float af = gv[c] * rs;
            afs[c] = af;
            cfs[c] = btv[c] - mu * af;
        }
        __syncthreads();
        const int f = (blockIdx.x - EPI_EDGE_BLOCKS) * 256 + threadIdx.x;  // 262144
        const int c = f & 31;
        out[f] = afs[c] * o_v[f] + cfs[c];
    } else {
        // zero third output: 1032192 floats = 258048 float4
        const int i4 = (blockIdx.x - EPI_EDGE_BLOCKS - EPI_NODE_BLOCKS) * 256 + threadIdx.x;
        *(float4*)(out + DV_SIZE + DE_SIZE + (size_t)i4 * 4) =
            make_float4(0.f, 0.f, 0.f, 0.f);
    }
}

// ---------------------------------------------------------------------------
extern "C" void kernel_launch(void* const* d_in, const int* in_sizes, int n_in,
                              void* d_out, int out_size, void* d_ws, size_t ws_size,
                              hipStream_t stream) {
    const float* v0 = (const float*)d_in[0];
    const float* e0 = (const float*)d_in[1];
    const float* etype = (const float*)d_in[2];
    const float* W1v = (const float*)d_in[3];
    const float* b1v = (const float*)d_in[4];
    const float* W2v = (const float*)d_in[5];
    const float* b2v = (const float*)d_in[6];
    const float* gv = (const float*)d_in[7];
    const float* btv = (const float*)d_in[8];
    const float* W1e = (const float*)d_in[9];
    const float* b1e = (const float*)d_in[10];
    const float* W2e = (const float*)d_in[11];
    const float* b2e = (const float*)d_in[12];
    const float* ge = (const float*)d_in[13];
    const float* bte = (const float*)d_in[14];
    float* out = (float*)d_out;

    // Workspace layout (floats)
    float* ws = (float*)d_ws;
    float* buckets = ws;                       // 4096  (edge BN buckets)
    float* nbuckets = ws + 4096;               // 2048  (node BN buckets)
    float* agg = ws + 6144;                    // 262144
    float* o_v = ws + 268288;                  // 262144
    unsigned short* v0bf = (unsigned short*)(ws + 530432);   // 262144 bf16 (131072 floats)
    unsigned short* o_e = (unsigned short*)(ws + 661504);    // 2*BE*32 bf16 = 66 MB

    prep_kernel<<<513, 256, 0, stream>>>(e0, agg, v0, v0bf, buckets);
    edge_stats_mfma_kernel<<<PBLK_A + NODE_BLOCKS, 512, 0, stream>>>(
        v0bf, W1e, b1e, W2e, b2e, buckets, o_e,
        agg, W1v, b1v, W2v, b2v, o_v, nbuckets);
    epilogue_kernel<<<EPI_EDGE_BLOCKS + EPI_NODE_BLOCKS + EPI_ZERO_BLOCKS, 256, 0, stream>>>(
        o_e, etype, buckets, ge, bte, o_v, nbuckets, gv, btv, out);
}

// Round 14
// 225.298 us; speedup vs baseline: 1.0706x; 1.0706x over previous
//
#include <hip/hip_runtime.h>
#include <hip/hip_bf16.h>

// Problem constants
#define NB 128       // batch (num_sims)
#define NA 64        // num_atoms
#define NE 4032      // edges = NA*(NA-1)
#define KT 2         // edge types
#define BE (NB * NE) // 516096 rows per edge type
#define DV_SIZE 262144
#define DE_SIZE 16515072
#define ZERO_SIZE 1032192

// Edge pass: 1008 blocks * 4 waves * 8 tiles * 16 rows = 516096.
// Grid-shape search EXHAUSTED: 504x512t=77us (r12), 1008x256t=65us (r10),
// 2016x256t=83-93us (r3/r8). 256-thread x 1136 blocks is the optimum.
#define PBLK_A 1008
#define TPW_A 8
#define NODE_BLOCKS 128   // appended to the edge grid (independent work)

#define PREP_ZERO_BASE 513
#define PREP_ZERO_BLOCKS 1008  // ZERO_SIZE / (256*4)

#define EPI_EDGE_BLOCKS 8064   // BE*4 / 256
#define EPI_NODE_BLOCKS 1024   // DV_SIZE / 256

typedef __attribute__((ext_vector_type(8))) short short8;
typedef __attribute__((ext_vector_type(4))) float floatx4;

__device__ __forceinline__ float elu(float x) {
    return x > 0.0f ? x : __expf(x) - 1.0f;
}

__device__ __forceinline__ unsigned short f2bf(float x) {  // RNE, one-time staging
    unsigned u = __float_as_uint(x);
    return (unsigned short)((u + 0x7FFFu + ((u >> 16) & 1u)) >> 16);
}

// packed f32x2 -> bf16x2 (RNE): low 16 = a, high 16 = b
__device__ __forceinline__ unsigned pkbf(float a, float b) {
    __hip_bfloat162 h = __float22bfloat162_rn(make_float2(a, b));
    unsigned u;
    __builtin_memcpy(&u, &h, 4);
    return u;
}

__device__ __forceinline__ short8 pack8(float4 a, float4 b) {
    unsigned u[4] = {pkbf(a.x, a.y), pkbf(a.z, a.w), pkbf(b.x, b.y), pkbf(b.z, b.w)};
    short8 r;
    __builtin_memcpy(&r, u, 16);
    return r;
}

// ===========================================================================
// PREP: agg (blocks 0..255, unroll 8) + v0->bf16 (256..511) + bucket zero
// (block 512) + third-output zero (blocks 513..1520 — moved here from the
// epilogue: depends on nothing, prep has idle store BW, epilogue sheds
// 1008 blocks from the critical tail).
// unroll-16 agg (r11) and 8192-block agg (r9) both measured SLOWER.
// ===========================================================================
__global__ __launch_bounds__(256) void prep_kernel(const float* __restrict__ e0,
                                                   float* __restrict__ agg,
                                                   const float* __restrict__ v0,
                                                   unsigned short* __restrict__ v0bf,
                                                   float* __restrict__ buckets,
                                                   float* __restrict__ out) {
    if (blockIdx.x < 256) {
        // agg[b,j,c4] = (1/64) * sum_{i != j} e0[b, i, pos(i,j), c4]
        const int f = blockIdx.x * 256 + threadIdx.x;  // 65536 = B*N*8
        const int c4 = f & 7;
        const int jn = (f >> 3) & 63;
        const int b = f >> 9;
        const float4* base = (const float4*)e0 + (size_t)b * 64 * 63 * 8;
        float x = 0.f, y = 0.f, z = 0.f, ww = 0.f;
#pragma unroll 8
        for (int i = 0; i < 64; i++) {
            int p = jn - (jn > i ? 1 : 0);
            p = p > 62 ? 62 : p;
            const float m = (i == jn) ? 0.0f : 1.0f;
            const float4 v = base[(i * 63 + p) * 8 + c4];
            x = fmaf(v.x, m, x);
            y = fmaf(v.y, m, y);
            z = fmaf(v.z, m, z);
            ww = fmaf(v.w, m, ww);
        }
        const float s = 1.0f / 64.0f;
        *(float4*)(agg + (size_t)f * 4) = make_float4(x * s, y * s, z * s, ww * s);
    } else if (blockIdx.x < 512) {
        const int idx = (blockIdx.x - 256) * 256 + threadIdx.x;  // 65536, 4 elems each
        const float4 v = reinterpret_cast<const float4*>(v0)[idx];
        uint2 r;
        r.x = pkbf(v.x, v.y);
        r.y = pkbf(v.z, v.w);
        reinterpret_cast<uint2*>(v0bf)[idx] = r;
    } else if (blockIdx.x == 512) {
        // zero edge+node BN buckets: 6144 floats = 1536 float4
#pragma unroll
        for (int it = 0; it < 6; it++) {
            const int i4 = it * 256 + threadIdx.x;
            *(float4*)(buckets + (size_t)i4 * 4) = make_float4(0.f, 0.f, 0.f, 0.f);
        }
    } else {
        // zero third output: 1032192 floats = 258048 float4
        const int i4 = (blockIdx.x - PREP_ZERO_BASE) * 256 + threadIdx.x;
        *(float4*)(out + DV_SIZE + DE_SIZE + (size_t)i4 * 4) =
            make_float4(0.f, 0.f, 0.f, 0.f);
    }
}

// ===========================================================================
// MERGED MFMA pass (round-10 proven, 65us): blocks [0,1008) = edge MLP
// (stage both k once, biases in LDS, TPW=8, unroll-2 tile loop);
// blocks [1008,1136) = node MLP (fills CU slots as edge blocks retire).
// History: 2016-block edge grids SLOWER (r3/r8); 504x512t SLOWER (r12);
// (256,6) spill disaster (r1); bias->VGPR+prefetch slower (r7). Keep (256,3).
// ===========================================================================
struct SMW {
    short8 wA1[16][64];  // f = ((k*4+mt)*2+kf)   16 KB
    short8 wA2[8][64];   // f = ((k*2+mt2)*2+kf)   8 KB
    float b1s[128];
    float b2s[64];
};
struct SME {
    SMW wk;
    unsigned hbuf[4][512];  // 8 KB, per-wave fc1->fc2 transpose buffer
};
struct SMN {
    short8 wA1n[4][64];
    short8 wA2n[4][64];
    float b1s[64];
    float b2s[32];
    unsigned long long hbuf[4][16 * 20];
};
union SMU {
    SME e;
    SMN n;
};

__device__ __forceinline__ void stage_weights(SMW& sm, const float* __restrict__ W1,
                                              const float* __restrict__ b1,
                                              const float* __restrict__ W2,
                                              const float* __restrict__ b2) {
    const int tid = threadIdx.x;
#pragma unroll
    for (int s = 0; s < 4; s++) {
        const int slot = s * 256 + tid;
        const int f = slot >> 6, l = slot & 63;
        const int k = f >> 3, mt = (f >> 1) & 3, kf = f & 1;
        const int g = l >> 4, m15 = l & 15;
        short8 v;
#pragma unroll
        for (int j = 0; j < 8; j++) {
            const int kk = kf * 32 + g * 8 + j;
            v[j] = (short)f2bf(W1[(k * 64 + kk) * 64 + mt * 16 + m15]);
        }
        sm.wA1[f][l] = v;
    }
#pragma unroll
    for (int s = 0; s < 2; s++) {
        const int slot = s * 256 + tid;
        const int f = slot >> 6, l = slot & 63;
        const int k = f >> 2, mt2 = (f >> 1) & 1, kf = f & 1;
        const int g = l >> 4, m15 = l & 15;
        short8 v;
#pragma unroll
        for (int j = 0; j < 8; j++) {
            const int kk = kf * 32 + g * 8 + j;
            v[j] = (short)f2bf(W2[(k * 64 + kk) * 32 + mt2 * 16 + m15]);
        }
        sm.wA2[f][l] = v;
    }
    if (tid < 128) sm.b1s[tid] = b1[tid];
    if (tid < 64) sm.b2s[tid] = b2[tid];
}

__device__ __forceinline__ void load_xfrags(const unsigned short* __restrict__ v0bf,
                                            int row, int g, short8& bx0, short8& bx1) {
    const int b = row / NE;
    const int e = row - b * NE;
    const int i = e / 63;
    const int p = e - i * 63;
    const int j = p + (p >= i ? 1 : 0);
    bx0 = *(const short8*)(v0bf + ((b * 64 + j) * 32 + g * 8));  // recv
    bx1 = *(const short8*)(v0bf + ((b * 64 + i) * 32 + g * 8));  // send
}

__global__ __launch_bounds__(256, 3) void edge_stats_mfma_kernel(
    const unsigned short* __restrict__ v0bf, const float* __restrict__ W1,
    const float* __restrict__ b1, const float* __restrict__ W2,
    const float* __restrict__ b2, float* __restrict__ buckets,
    unsigned short* __restrict__ o_e, const float* __restrict__ agg,
    const float* __restrict__ W1v, const float* __restrict__ b1v,
    const float* __restrict__ W2v, const float* __restrict__ b2v,
    float* __restrict__ o_v, float* __restrict__ nbuckets) {
    __shared__ SMU u;
    const int lane = threadIdx.x & 63;
    const int w = threadIdx.x >> 6;
    const int g = lane >> 4, m15 = lane & 15;

    if (blockIdx.x < PBLK_A) {
        // ================= EDGE PATH =================
        SME& sm = u.e;
        stage_weights(sm.wk, W1, b1, W2, b2);
        __syncthreads();

        const int gw = blockIdx.x * 4 + w;
        unsigned* hw = &sm.hbuf[w][0];
        const int sw = m15 & 7;            // hbuf XOR-swizzle key
        const int rbase = m15 * 32;

#pragma unroll 1
        for (int k = 0; k < 2; k++) {
            // weight frags -> registers (invariant across tiles): 12 short8 = 48 VGPR
            short8 a1r[4][2], a2r[2][2];
#pragma unroll
            for (int mt = 0; mt < 4; mt++)
#pragma unroll
                for (int kf = 0; kf < 2; kf++)
                    a1r[mt][kf] = sm.wk.wA1[(k * 4 + mt) * 2 + kf][lane];
#pragma unroll
            for (int mt2 = 0; mt2 < 2; mt2++)
#pragma unroll
                for (int kf = 0; kf < 2; kf++)
                    a2r[mt2][kf] = sm.wk.wA2[(k * 2 + mt2) * 2 + kf][lane];

            float st[2][4], sq[2][4];
#pragma unroll
            for (int m = 0; m < 2; m++)
#pragma unroll
                for (int r = 0; r < 4; r++) { st[m][r] = 0.f; sq[m][r] = 0.f; }

#pragma unroll 2
            for (int tt = 0; tt < TPW_A; tt++) {
                const int row = (gw * TPW_A + tt) * 16 + m15;
                short8 bx0, bx1;
                load_xfrags(v0bf, row, g, bx0, bx1);

#pragma unroll
                for (int mt = 0; mt < 4; mt++) {
                    const float4 bb = *(const float4*)&sm.wk.b1s[k * 64 + mt * 16 + 4 * g];
                    floatx4 acc = {bb.x, bb.y, bb.z, bb.w};
                    acc = __builtin_amdgcn_mfma_f32_16x16x32_bf16(a1r[mt][0], bx0, acc, 0, 0, 0);
                    acc = __builtin_amdgcn_mfma_f32_16x16x32_bf16(a1r[mt][1], bx1, acc, 0, 0, 0);
                    uint2 hv;
                    hv.x = pkbf(elu(acc[0]), elu(acc[1]));
                    hv.y = pkbf(elu(acc[2]), elu(acc[3]));
                    const int q = 2 * mt + (g >> 1);
                    *(uint2*)&hw[rbase + ((q ^ sw) << 2) + 2 * (g & 1)] = hv;
                }
                const short8 bh0 = *(const short8*)&hw[rbase + (((g) ^ sw) << 2)];
                const short8 bh1 = *(const short8*)&hw[rbase + (((g + 4) ^ sw) << 2)];
#pragma unroll
                for (int mt2 = 0; mt2 < 2; mt2++) {
                    const float4 bb = *(const float4*)&sm.wk.b2s[k * 32 + mt2 * 16 + 4 * g];
                    floatx4 acc = {bb.x, bb.y, bb.z, bb.w};
                    acc = __builtin_amdgcn_mfma_f32_16x16x32_bf16(a2r[mt2][0], bh0, acc, 0, 0, 0);
                    acc = __builtin_amdgcn_mfma_f32_16x16x32_bf16(a2r[mt2][1], bh1, acc, 0, 0, 0);
                    float v0v = elu(acc[0]), v1v = elu(acc[1]);
                    float v2v = elu(acc[2]), v3v = elu(acc[3]);
                    st[mt2][0] += v0v; sq[mt2][0] += v0v * v0v;
                    st[mt2][1] += v1v; sq[mt2][1] += v1v * v1v;
                    st[mt2][2] += v2v; sq[mt2][2] += v2v * v2v;
                    st[mt2][3] += v3v; sq[mt2][3] += v3v * v3v;
                    uint2 ov;
                    ov.x = pkbf(v0v, v1v);
                    ov.y = pkbf(v2v, v3v);
                    *(uint2*)(o_e + ((size_t)k * BE + row) * 32 + mt2 * 16 + 4 * g) = ov;
                }
            }

            // flush stats for this k
            const int bk = gw & 31;
#pragma unroll
            for (int m = 0; m < 2; m++)
#pragma unroll
                for (int r = 0; r < 4; r++) {
                    float s = st[m][r], ss = sq[m][r];
#pragma unroll
                    for (int off = 1; off < 16; off <<= 1) {
                        s += __shfl_xor(s, off, 64);
                        ss += __shfl_xor(ss, off, 64);
                    }
                    if (m15 == 0) {
                        const int ch = m * 16 + 4 * g + r;
                        atomicAdd(&buckets[((bk * KT + k) * 32 + ch) * 2], s);
                        atomicAdd(&buckets[((bk * KT + k) * 32 + ch) * 2 + 1], ss);
                    }
                }
        }
    } else {
        // ================= NODE PATH =================
        SMN& sm = u.n;
        const int tid = threadIdx.x;
        {
            const int f = tid >> 6, l = tid & 63;
            const int gg = l >> 4, mm = l & 15;
            short8 v;
#pragma unroll
            for (int j = 0; j < 8; j++)
                v[j] = (short)f2bf(W1v[(gg * 8 + j) * 64 + f * 16 + mm]);
            sm.wA1n[f][l] = v;
            const int mt2 = f >> 1, kf = f & 1;
            short8 uu;
#pragma unroll
            for (int j = 0; j < 8; j++)
                uu[j] = (short)f2bf(W2v[(kf * 32 + gg * 8 + j) * 32 + mt2 * 16 + mm]);
            sm.wA2n[f][l] = uu;
        }
        if (tid < 64) sm.b1s[tid] = b1v[tid];
        else if (tid < 96) sm.b2s[tid - 64] = b2v[tid - 64];
        __syncthreads();

        const int tile = (blockIdx.x - PBLK_A) * 4 + w;  // 512 tiles
        const int row = tile * 16 + m15;

        const float4* px = (const float4*)(agg + (size_t)row * 32 + g * 8);
        const short8 bx = pack8(px[0], px[1]);

        const char* hbase = (const char*)&sm.hbuf[w][0];
        unsigned long long* hw = &sm.hbuf[w][0];

#pragma unroll
        for (int mt = 0; mt < 4; mt++) {
            const float4 bb = *(const float4*)&sm.b1s[mt * 16 + 4 * g];
            floatx4 acc = {bb.x, bb.y, bb.z, bb.w};
            acc = __builtin_amdgcn_mfma_f32_16x16x32_bf16(sm.wA1n[mt][lane], bx, acc, 0, 0, 0);
            const unsigned lo = pkbf(elu(acc[0]), elu(acc[1]));
            const unsigned hi = pkbf(elu(acc[2]), elu(acc[3]));
            hw[m15 * 20 + mt * 4 + g] = ((unsigned long long)hi << 32) | lo;
        }
        const short8 bh0 = *(const short8*)(hbase + m15 * 160 + 0 + g * 16);
        const short8 bh1 = *(const short8*)(hbase + m15 * 160 + 64 + g * 16);

        const int bk = tile & 31;
#pragma unroll
        for (int mt2 = 0; mt2 < 2; mt2++) {
            const float4 bb = *(const float4*)&sm.b2s[mt2 * 16 + 4 * g];
            floatx4 acc = {bb.x, bb.y, bb.z, bb.w};
            acc = __builtin_amdgcn_mfma_f32_16x16x32_bf16(sm.wA2n[mt2 * 2 + 0][lane], bh0, acc, 0, 0, 0);
            acc = __builtin_amdgcn_mfma_f32_16x16x32_bf16(sm.wA2n[mt2 * 2 + 1][lane], bh1, acc, 0, 0, 0);
            float4 ov;
            ov.x = elu(acc[0]);
            ov.y = elu(acc[1]);
            ov.z = elu(acc[2]);
            ov.w = elu(acc[3]);
            *(float4*)(o_v + (size_t)row * 32 + mt2 * 16 + 4 * g) = ov;
            const float vv[4] = {ov.x, ov.y, ov.z, ov.w};
#pragma unroll
            for (int r = 0; r < 4; r++) {
                float s = vv[r], ss = vv[r] * vv[r];
#pragma unroll
                for (int off = 1; off < 16; off <<= 1) {
                    s += __shfl_xor(s, off, 64);
                    ss += __shfl_xor(ss, off, 64);
                }
                if (m15 == 0) {
                    const int ch = mt2 * 16 + 4 * g + r;
                    atomicAdd(&nbuckets[(bk * 32 + ch) * 2], s);
                    atomicAdd(&nbuckets[(bk * 32 + ch) * 2 + 1], ss);
                }
            }
        }
    }
}

// ===========================================================================
// EPILOGUE (round-10 proven, minus the zero section now in prep):
// blocks [0,8064) edge BN-affine+etype -> de;
// blocks [8064,9088) node BN-affine -> dv.
// 4-chunk grid-stride (r11) measured SLOWER — do not re-attempt.
// ===========================================================================
__global__ __launch_bounds__(256) void epilogue_kernel(
    const unsigned short* __restrict__ o_e, const float* __restrict__ etype,
    const float* __restrict__ buckets, const float* __restrict__ ge,
    const float* __restrict__ bte, const float* __restrict__ o_v,
    const float* __restrict__ nbuckets, const float* __restrict__ gv,
    const float* __restrict__ btv, float* __restrict__ out) {
    __shared__ float afs[64], cfs[64];

    if (blockIdx.x < EPI_EDGE_BLOCKS) {
        if (threadIdx.x < 64) {
            const int k = threadIdx.x >> 5, c = threadIdx.x & 31;
            float s = 0.0f, ss = 0.0f;
#pragma unroll
            for (int bk = 0; bk < 32; bk++) {
                s += buckets[((bk * KT + k) * 32 + c) * 2];
                ss += buckets[((bk * KT + k) * 32 + c) * 2 + 1];
            }
            const float M = (float)BE;
            const float mu = s / M;
            const float var = ss / M - mu * mu;
            const float rs = rsqrtf(var + 1e-5f);
            const float af = ge[k * 32 + c] * rs;
            afs[threadIdx.x] = af;
            cfs[threadIdx.x] = bte[k * 32 + c] - mu * af;
        }
        __syncthreads();

        float* de = out + DV_SIZE;
        const int t = blockIdx.x * 256 + threadIdx.x;  // BE*4 = 2064384
        const int cg = t & 3;
        const int row = t >> 2;
        const uint4 p0 = *(const uint4*)(o_e + (size_t)row * 32 + cg * 8);
        const uint4 p1 = *(const uint4*)(o_e + ((size_t)BE + row) * 32 + cg * 8);
        const float2 wv = *(const float2*)(etype + (size_t)row * 2);
        const unsigned pu0[4] = {p0.x, p0.y, p0.z, p0.w};
        const unsigned pu1[4] = {p1.x, p1.y, p1.z, p1.w};

        float r[8];
#pragma unroll
        for (int uu = 0; uu < 8; uu++) {
            const int ch = cg * 8 + uu;
            const float o0 = __uint_as_float((uu & 1) ? (pu0[uu >> 1] & 0xFFFF0000u)
                                                      : (pu0[uu >> 1] << 16));
            const float o1 = __uint_as_float((uu & 1) ? (pu1[uu >> 1] & 0xFFFF0000u)
                                                      : (pu1[uu >> 1] << 16));
            r[uu] = wv.x * fmaf(afs[ch], o0, cfs[ch]) +
                    wv.y * fmaf(afs[32 + ch], o1, cfs[32 + ch]);
        }
        float4* dst = (float4*)(de + (size_t)row * 32 + cg * 8);
        dst[0] = make_float4(r[0], r[1], r[2], r[3]);
        dst[1] = make_float4(r[4], r[5], r[6], r[7]);
    } else {
        if (threadIdx.x < 32) {
            const int c = threadIdx.x;
            float s = 0.0f, ss = 0.0f;
#pragma unroll
            for (int bk = 0; bk < 32; bk++) {
                s += nbuckets[(bk * 32 + c) * 2];
                ss += nbuckets[(bk * 32 + c) * 2 + 1];
            }
            const float M = 8192.0f;
            const float mu = s / M;
            const float var = ss / M - mu * mu;
            const float rs = rsqrtf(var + 1e-5f);
            const float af = gv[c] * rs;
            afs[c] = af;
            cfs[c] = btv[c] - mu * af;
        }
        __syncthreads();
        const int f = (blockIdx.x - EPI_EDGE_BLOCKS) * 256 + threadIdx.x;  // 262144
        const int c = f & 31;
        out[f] = afs[c] * o_v[f] + cfs[c];
    }
}

// ---------------------------------------------------------------------------
extern "C" void kernel_launch(void* const* d_in, const int* in_sizes, int n_in,
                              void* d_out, int out_size, void* d_ws, size_t ws_size,
                              hipStream_t stream) {
    const float* v0 = (const float*)d_in[0];
    const float* e0 = (const float*)d_in[1];
    const float* etype = (const float*)d_in[2];
    const float* W1v = (const float*)d_in[3];
    const float* b1v = (const float*)d_in[4];
    const float* W2v = (const float*)d_in[5];
    const float* b2v = (const float*)d_in[6];
    const float* gv = (const float*)d_in[7];
    const float* btv = (const float*)d_in[8];
    const float* W1e = (const float*)d_in[9];
    const float* b1e = (const float*)d_in[10];
    const float* W2e = (const float*)d_in[11];
    const float* b2e = (const float*)d_in[12];
    const float* ge = (const float*)d_in[13];
    const float* bte = (const float*)d_in[14];
    float* out = (float*)d_out;

    // Workspace layout (floats)
    float* ws = (float*)d_ws;
    float* buckets = ws;                       // 4096  (edge BN buckets)
    float* nbuckets = ws + 4096;               // 2048  (node BN buckets)
    float* agg = ws + 6144;                    // 262144
    float* o_v = ws + 268288;                  // 262144
    unsigned short* v0bf = (unsigned short*)(ws + 530432);   // 262144 bf16 (131072 floats)
    unsigned short* o_e = (unsigned short*)(ws + 661504);    // 2*BE*32 bf16 = 66 MB

    prep_kernel<<<PREP_ZERO_BASE + PREP_ZERO_BLOCKS, 256, 0, stream>>>(
        e0, agg, v0, v0bf, buckets, out);
    edge_stats_mfma_kernel<<<PBLK_A + NODE_BLOCKS, 256, 0, stream>>>(
        v0bf, W1e, b1e, W2e, b2e, buckets, o_e,
        agg, W1v, b1v, W2v, b2v, o_v, nbuckets);
    epilogue_kernel<<<EPI_EDGE_BLOCKS + EPI_NODE_BLOCKS, 256, 0, stream>>>(
        o_e, etype, buckets, ge, bte, o_v, nbuckets, gv, btv, out);
}